// Round 5
// baseline (1595.792 us; speedup 1.0000x reference)
//
#include <hip/hip_runtime.h>
#include <math.h>

#define BB 64
#define TT 2048
#define ADIM 384
#define NE 10    // num_embeddings == LSTM hidden
#define NG 40    // 4*NE gates
#define HD 3     // hidden_dim (codebook width)

// ---------------- workspace layout (bytes) ----------------
#define OFF_X64   0ULL
#define OFF_W64T  41943040ULL                 // ADIM*NG*8 = 122880
#define OFF_MADD  (OFF_W64T + 122880ULL)      // NG*3*8   = 960
#define OFF_ADD0  (OFF_MADD + 960ULL)         // NG*8     = 320  (bias only, t==0)
#define OFF_ADD1  (OFF_ADD0 + 320ULL)         // NG*8     = 320  (bias+qb, t>0)
#define OFF_H     (OFF_ADD1 + 320ULL)         // BB*TT*NE*4 = 5242880
#define OFF_IDX   (OFF_H + 5242880ULL)        // BB*TT*4  = 524288
#define OFF_PART  (OFF_IDX + 524288ULL)       // 512*8

// ---------------- fast f64 helpers ----------------
__device__ __forceinline__ double rcp1(double d) {   // seed + 1 NR: err ~1 ulp
    double r = __builtin_amdgcn_rcp(d);
    double e = fma(-d, r, 1.0);
    return fma(r, e, r);
}

template<int CTRL, int RMASK>
__device__ __forceinline__ double dpp_mov_f64(double x) {
    int lo = __double2loint(x), hi = __double2hiint(x);
    lo = __builtin_amdgcn_update_dpp(lo, lo, CTRL, RMASK, 0xF, true);
    hi = __builtin_amdgcn_update_dpp(hi, hi, CTRL, RMASK, 0xF, true);
    return __hiloint2double(hi, lo);
}

// 2^(v*L): single-fma exact reduction, deg-8 Estrin (rel err ~2e-10),
// integer ldexp (exponent-field add). Valid for |v*L| < ~600.
#define EXP2F64(res, v, L)                                                 \
    {                                                                      \
        const double MAGIC_ = 6755399441055744.0;  /* 1.5*2^52 */          \
        double sh_ = fma((v), (L), MAGIC_);                                \
        double n_  = sh_ - MAGIC_;                                         \
        int ni_ = __double2loint(sh_);                                     \
        double r_ = fma((v), (L), -n_);                                    \
        double r2_ = r_ * r_;                                              \
        double Q0_ = fma(r_, 0.6931471805599453, 1.0);                     \
        double Q1_ = fma(r_, 0.05550410866482158, 0.24022650695910072);    \
        double Q2_ = fma(r_, 0.0013333558146428443, 0.009618129107628477); \
        double Q3_ = fma(r_, 1.525273380405984e-5, 1.5403530393381606e-4); \
        double r4_ = r2_ * r2_;                                            \
        double R0_ = fma(r2_, Q1_, Q0_);                                   \
        double S1_ = fma(r2_, Q3_, Q2_);                                   \
        double S2_ = fma(r4_, 1.3215486790144307e-6, S1_);                 \
        double P_  = fma(r4_, S2_, R0_);                                   \
        int ph_ = __double2hiint(P_) + (ni_ << 20);                        \
        res = __hiloint2double(ph_, __double2loint(P_));                   \
    }

// ---------------- setup: W_ih^T (f64), M = W_ih@qs_W, bias tables ---------
__global__ __launch_bounds__(256) void setup_kernel(
        const float* __restrict__ W_ih, const float* __restrict__ qs_W,
        const float* __restrict__ qs_b, const float* __restrict__ b_ih,
        const float* __restrict__ b_hh,
        double* __restrict__ W64T, double* __restrict__ MADD,
        double* __restrict__ ADD0, double* __restrict__ ADD1) {
    int tid = threadIdx.x;
    if (blockIdx.x == 0) {
        if (tid < NG) {
            int k = tid;
            double M0 = 0, M1 = 0, M2 = 0, qb = 0;
            for (int a = 0; a < ADIM; ++a) {
                double w = (double)W_ih[k * ADIM + a];
                M0 = fma(w, (double)qs_W[a * HD + 0], M0);
                M1 = fma(w, (double)qs_W[a * HD + 1], M1);
                M2 = fma(w, (double)qs_W[a * HD + 2], M2);
                qb = fma(w, (double)qs_b[a], qb);
            }
            MADD[k * 3 + 0] = M0;
            MADD[k * 3 + 1] = M1;
            MADD[k * 3 + 2] = M2;
            double bias = (double)b_ih[k] + (double)b_hh[k];
            ADD0[k] = bias;        // t == 0: no qs path
            ADD1[k] = bias + qb;   // t  > 0: qs_b @ W_ih^T folded in
        }
    } else {
        int i = (blockIdx.x - 1) * 256 + tid;   // 60*256 == ADIM*NG exactly
        int a = i / NG, kk = i % NG;
        W64T[i] = (double)W_ih[kk * ADIM + a];
    }
}

// ---------------- X = hs @ W_ih.T + bias(+qb)  (f64 accumulate) -----------
__global__ __launch_bounds__(256) void gemm_kernel(
        const float* __restrict__ hs, const double* __restrict__ W64T,
        const double* __restrict__ ADD0, const double* __restrict__ ADD1,
        double* __restrict__ X64) {
    int lane = threadIdx.x & 63;
    int wv = threadIdx.x >> 6;
    int cb = __builtin_amdgcn_readfirstlane(wv * 10);   // wave-uniform col base
    long row = (long)blockIdx.x * 64 + lane;            // < 131072
    const float* xr = hs + row * ADIM;
    double acc[10];
#pragma unroll
    for (int j = 0; j < 10; ++j) acc[j] = 0.0;
    for (int a0 = 0; a0 < ADIM; a0 += 4) {
        float4 xv = *(const float4*)(xr + a0);
#pragma unroll
        for (int u = 0; u < 4; ++u) {
            double xd = (double)((&xv.x)[u]);
            const double* wp = W64T + (a0 + u) * NG + cb;  // uniform -> broadcast
#pragma unroll
            for (int j = 0; j < 10; ++j) acc[j] = fma(wp[j], xd, acc[j]);
        }
    }
    int trow = (int)(row & (TT - 1));
    double* op = X64 + row * NG + cb;
#pragma unroll
    for (int j = 0; j < 10; ++j) {
        double a0j = ADD0[cb + j], a1j = ADD1[cb + j];
        op[j] = acc[j] + (trow == 0 ? a0j : a1j);
    }
}

// ---------------- sequential recurrence: one wave per batch ----------------
// QUAD layout: lane 4m+j holds gate j (i,f,g,o) of embedding m. Valid c/h
// live only on j==0 lanes (j!=0 garbage is never consumed). Argmax runs on
// the SCALAR unit from the (uniform) readlane'd h words; esel comes from the
// rank-3 decomposition codebook[s_idx] @ M[col] (bias+qb folded into X64).
__global__ __launch_bounds__(64) void recur_kernel(
        const double* __restrict__ X64,
        const float* __restrict__ W_hh, const double* __restrict__ MADD,
        const float* __restrict__ codebook,
        float* __restrict__ h_out, int* __restrict__ idx_out) {
    const int k = threadIdx.x;
    const int b = blockIdx.x;
    const int j = k & 3;                 // gate type 0..3 = i,f,g,o
    const int m = k >> 2;                // embedding index (valid < 10)
    const bool valid = (k < NG);
    const int col = valid ? (j * 10 + m) : (NG - 1);
    const bool isg = (j == 2);

    const double LOG2E = 1.4426950408889634074;
    // i/f/o: e1 = e^{-gate} -> act = 1/(1+e1)          (amul=1,  aadd=0)
    // g:     e1 = e^{+2gate} -> act = 1 - 2/(1+e1)     (amul=-2, aadd=1)
    const double Lg   = isg ? (2.0 * LOG2E) : (-LOG2E);
    const double amul = isg ? -2.0 : 1.0;
    const double aadd = isg ? 1.0 : 0.0;
    const double L2   = 2.0 * LOG2E;     // tanh(c) side: e^{2|c|}

    double whh[NE];
#pragma unroll
    for (int mm = 0; mm < NE; ++mm) whh[mm] = (double)W_hh[col * NE + mm];
    double M0v = MADD[col * 3 + 0];
    double M1v = MADD[col * 3 + 1];
    double M2v = MADD[col * 3 + 2];

    float cbf[NE * HD];                  // 30 uniform scalars
#pragma unroll
    for (int i = 0; i < NE * HD; ++i) cbf[i] = codebook[i];

    const double* Xb = X64 + (long)b * TT * NG;
    float* hob = h_out + (long)b * TT * NE;
    int* iob = idx_out + (long)b * TT;

    // prefetch ring depth 4 (overrun past t=TT reads allocated ws; unused)
    double xs0 = Xb[0 * NG + col];
    double xs1 = Xb[1 * NG + col];
    double xs2 = Xb[2 * NG + col];
    double xs3 = Xb[3 * NG + col];

    double ha[NE];
#pragma unroll
    for (int mm = 0; mm < NE; ++mm) ha[mm] = 0.0;
    double c = 0.0;
    double cb0 = 0.0, cb1 = 0.0, cb2 = 0.0;   // codebook[prev idx], 0 at t=0

    auto step = [&](double& xslot, int t) {
        double xg = xslot;
        xslot = Xb[(long)(t + 4) * NG + col];

        // gate = xg(+bias+qb) + <h_prev, W_hh[col,:]> + codebook[idx]·M[col]
        double p0 = fma(ha[1], whh[1], ha[0] * whh[0]);
        double p1 = fma(ha[3], whh[3], ha[2] * whh[2]);
        double p2 = fma(ha[5], whh[5], ha[4] * whh[4]);
        double p3 = fma(ha[7], whh[7], ha[6] * whh[6]);
        double p4 = fma(ha[9], whh[9], ha[8] * whh[8]);
        double dot = ((p0 + p1) + (p2 + p3)) + p4;
        double esel = fma(cb2, M2v, fma(cb1, M1v, cb0 * M0v));
        double gate = (xg + dot) + esel;

        double e1;
        EXP2F64(e1, gate, Lg);
        double r1 = rcp1(1.0 + e1);
        double act = fma(amul, r1, aadd);

        // quad gather (j==0 lanes get f,g,o; own act = i). j!=0 garbage OK.
        double ffv = dpp_mov_f64<0x55, 0xF>(act);
        double fgv = dpp_mov_f64<0xAA, 0xF>(act);
        double fov = dpp_mov_f64<0xFF, 0xF>(act);
        c = fma(ffv, c, act * fgv);

        double e2;
        EXP2F64(e2, fabs(c), L2);
        double r2t = rcp1(1.0 + e2);
        double th = fma(-2.0, r2t, 1.0);          // tanh(|c|)
        double habs = fov * th;
        int hlo = __double2loint(habs);
        int hhi = (__double2hiint(habs) & 0x7fffffff) |
                  (__double2hiint(c) & 0x80000000);  // sign(h)=sign(c)

        // broadcast h (lanes 4m) into uniform regs -> ha + SALU argmax keys
        int lo_[NE], hi_[NE];
#pragma unroll
        for (int mm = 0; mm < NE; ++mm) {
            lo_[mm] = __builtin_amdgcn_readlane(hlo, 4 * mm);
            hi_[mm] = __builtin_amdgcn_readlane(hhi, 4 * mm);
            ha[mm] = __hiloint2double(hi_[mm], lo_[mm]);
        }
        // sortable-int transform (monotone for ordered doubles)
        unsigned kh[NE], kl[NE];
#pragma unroll
        for (int mm = 0; mm < NE; ++mm) {
            unsigned msk = (unsigned)(hi_[mm] >> 31);
            kh[mm] = ((unsigned)hi_[mm]) ^ (msk | 0x80000000u);
            kl[mm] = ((unsigned)lo_[mm]) ^ msk;
        }
        // 9-node scalar tree; right wins only if strictly greater
        // (first-index-wins, matching jnp.argmax)
#define NODE(aH, aL, aI, bH, bL, bI, oH, oL, oI)                      \
        {                                                             \
            bool gt_ = (bH > aH) || ((bH == aH) && (bL > aL));        \
            oH = gt_ ? bH : aH; oL = gt_ ? bL : aL; oI = gt_ ? bI : aI; \
        }
        unsigned w01H, w01L, w23H, w23L, w45H, w45L, w67H, w67L, w89H, w89L;
        int w01I, w23I, w45I, w67I, w89I;
        NODE(kh[0], kl[0], 0, kh[1], kl[1], 1, w01H, w01L, w01I);
        NODE(kh[2], kl[2], 2, kh[3], kl[3], 3, w23H, w23L, w23I);
        NODE(kh[4], kl[4], 4, kh[5], kl[5], 5, w45H, w45L, w45I);
        NODE(kh[6], kl[6], 6, kh[7], kl[7], 7, w67H, w67L, w67I);
        NODE(kh[8], kl[8], 8, kh[9], kl[9], 9, w89H, w89L, w89I);
        unsigned x03H, x03L, x47H, x47L, y07H, y07L, sH, sL;
        int x03I, x47I, y07I, s_idx;
        NODE(w01H, w01L, w01I, w23H, w23L, w23I, x03H, x03L, x03I);
        NODE(w45H, w45L, w45I, w67H, w67L, w67I, x47H, x47L, x47I);
        NODE(x03H, x03L, x03I, x47H, x47L, x47I, y07H, y07L, y07I);
        NODE(y07H, y07L, y07I, w89H, w89L, w89I, sH, sL, s_idx);
#undef NODE

        // codebook[s_idx] select (uniform f32, 4-level bit tree) + cvt
#define SEL10(res, A)                                                  \
        {                                                              \
            float t0_ = (s_idx & 1) ? A[3 + 0] : A[0 + 0];             \
            float t1_ = (s_idx & 1) ? A[9 + 0] : A[6 + 0];             \
            float t2_ = (s_idx & 1) ? A[15 + 0] : A[12 + 0];           \
            float t3_ = (s_idx & 1) ? A[21 + 0] : A[18 + 0];           \
            float t4_ = (s_idx & 1) ? A[27 + 0] : A[24 + 0];           \
            float u0_ = (s_idx & 2) ? t1_ : t0_;                       \
            float u1_ = (s_idx & 2) ? t3_ : t2_;                       \
            float v0_ = (s_idx & 4) ? u1_ : u0_;                       \
            res = (double)((s_idx & 8) ? t4_ : v0_);                   \
        }
        { const float* A = cbf + 0; SEL10(cb0, A); }
        { const float* A = cbf + 1; SEL10(cb1, A); }
        { const float* A = cbf + 2; SEL10(cb2, A); }
#undef SEL10

        // store h (lanes 4m, m<10) and idx (lane 40) in one masked store
        if ((k & 3) == 0 && k <= NG) {
            double hd = __hiloint2double(hhi, hlo);
            int val = valid ? __float_as_int((float)hd) : s_idx;
            int* ap = valid ? ((int*)hob + (long)t * NE + m) : (iob + t);
            *ap = val;
        }
    };

    for (int t = 0; t < TT; t += 4) {
        step(xs0, t);
        step(xs1, t + 1);
        step(xs2, t + 2);
        step(xs3, t + 3);
    }
}

// ---------------- deferred: embs gather + NLL partial sums ----------------
__global__ __launch_bounds__(256) void tail_kernel(
        const float* __restrict__ h_ws, const int* __restrict__ idx_ws,
        const int* __restrict__ inds, const float* __restrict__ codebook,
        float* __restrict__ out_embs, double* __restrict__ partials) {
    int i = blockIdx.x * 256 + threadIdx.x;   // 512*256 == 131072 exactly
    int idx = idx_ws[i];
    out_embs[i * 3 + 0] = codebook[idx * 3 + 0];
    out_embs[i * 3 + 1] = codebook[idx * 3 + 1];
    out_embs[i * 3 + 2] = codebook[idx * 3 + 2];

    const float* hp = h_ws + (long)i * NE;
    double hv[NE];
#pragma unroll
    for (int mm = 0; mm < NE; ++mm) hv[mm] = (double)hp[mm];
    double mx = hv[0];
#pragma unroll
    for (int mm = 1; mm < NE; ++mm) mx = fmax(mx, hv[mm]);
    double sdn = 0.0;
#pragma unroll
    for (int mm = 0; mm < NE; ++mm) sdn += exp(hv[mm] - mx);
    int ind = inds[i];
    double picked = (double)hp[ind] - (mx + log(sdn));

    __shared__ double red[256];
    red[threadIdx.x] = picked;
    __syncthreads();
    for (int st = 128; st > 0; st >>= 1) {
        if (threadIdx.x < st) red[threadIdx.x] += red[threadIdx.x + st];
        __syncthreads();
    }
    if (threadIdx.x == 0) partials[blockIdx.x] = red[0];
}

__global__ __launch_bounds__(256) void final_kernel(
        const double* __restrict__ partials, float* __restrict__ out_loss) {
    __shared__ double red[256];
    red[threadIdx.x] = partials[threadIdx.x] + partials[threadIdx.x + 256];
    __syncthreads();
    for (int st = 128; st > 0; st >>= 1) {
        if (threadIdx.x < st) red[threadIdx.x] += red[threadIdx.x + st];
        __syncthreads();
    }
    if (threadIdx.x == 0)
        out_loss[0] = (float)(-red[0] / (double)(BB * TT));
}

extern "C" void kernel_launch(void* const* d_in, const int* in_sizes, int n_in,
                              void* d_out, int out_size, void* d_ws, size_t ws_size,
                              hipStream_t stream) {
    const float* hs       = (const float*)d_in[0];
    const int*   inds     = (const int*)d_in[1];
    const float* codebook = (const float*)d_in[2];
    const float* W_ih     = (const float*)d_in[3];
    const float* W_hh     = (const float*)d_in[4];
    const float* b_ih     = (const float*)d_in[5];
    const float* b_hh     = (const float*)d_in[6];
    const float* qs_W     = (const float*)d_in[7];
    const float* qs_b     = (const float*)d_in[8];
    float* out = (float*)d_out;

    char* ws = (char*)d_ws;
    double* X64   = (double*)(ws + OFF_X64);
    double* W64T  = (double*)(ws + OFF_W64T);
    double* MADD  = (double*)(ws + OFF_MADD);
    double* ADD0  = (double*)(ws + OFF_ADD0);
    double* ADD1  = (double*)(ws + OFF_ADD1);
    float*  h_ws  = (float*)(ws + OFF_H);
    int*    idx_ws= (int*)(ws + OFF_IDX);
    double* part  = (double*)(ws + OFF_PART);

    setup_kernel<<<61, 256, 0, stream>>>(W_ih, qs_W, qs_b, b_ih, b_hh,
                                         W64T, MADD, ADD0, ADD1);
    gemm_kernel<<<2048, 256, 0, stream>>>(hs, W64T, ADD0, ADD1, X64);
    recur_kernel<<<BB, 64, 0, stream>>>(X64, W_hh, MADD, codebook, h_ws, idx_ws);
    tail_kernel<<<512, 256, 0, stream>>>(h_ws, idx_ws, inds, codebook, out, part);
    final_kernel<<<1, 256, 0, stream>>>(part, out + (size_t)BB * TT * HD);
}

// Round 6
// 885.016 us; speedup vs baseline: 1.8031x; 1.8031x over previous
//
#include <hip/hip_runtime.h>
#include <math.h>

#define BB 64
#define TT 2048
#define ADIM 384
#define NE 10    // num_embeddings == LSTM hidden
#define NG 40    // 4*NE gates
#define HD 3     // hidden_dim (codebook width)

// ---------------- workspace layout (bytes) ----------------
#define OFF_X64   0ULL
#define OFF_W64T  41943040ULL                 // ADIM*NG*8 = 122880
#define OFF_ETAB  (OFF_W64T + 122880ULL)      // NE*NG*8  = 3200 (codebook@M, NO qb)
#define OFF_ADD0  (OFF_ETAB + 3200ULL)        // NG*8     = 320  (bias, t==0)
#define OFF_ADD1  (OFF_ADD0 + 320ULL)         // NG*8     = 320  (bias+qb, t>0)
#define OFF_H     (OFF_ADD1 + 320ULL)         // BB*TT*NE*4 = 5242880
#define OFF_IDX   (OFF_H + 5242880ULL)        // BB*TT*4  = 524288
#define OFF_PART  (OFF_IDX + 524288ULL)       // 512*8

// ---------------- fast f64 helpers ----------------
__device__ __forceinline__ double rcp1(double d) {   // seed + 1 NR: err ~1 ulp
    double r = __builtin_amdgcn_rcp(d);
    double e = fma(-d, r, 1.0);
    return fma(r, e, r);
}

template<int CTRL, int RMASK>
__device__ __forceinline__ double dpp_mov_f64(double x) {
    int lo = __double2loint(x), hi = __double2hiint(x);
    lo = __builtin_amdgcn_update_dpp(lo, lo, CTRL, RMASK, 0xF, true);
    hi = __builtin_amdgcn_update_dpp(hi, hi, CTRL, RMASK, 0xF, true);
    return __hiloint2double(hi, lo);
}

// 2^(v*L): single-fma exact reduction, deg-8 Estrin (rel err ~2e-10),
// integer ldexp (exponent-field add). Valid for |v*L| < ~600.
// Validated R5 (absmax 0 on full trajectory).
#define EXP2F64(res, v, L)                                                 \
    {                                                                      \
        const double MAGIC_ = 6755399441055744.0;  /* 1.5*2^52 */          \
        double sh_ = fma((v), (L), MAGIC_);                                \
        double n_  = sh_ - MAGIC_;                                         \
        int ni_ = __double2loint(sh_);                                     \
        double r_ = fma((v), (L), -n_);                                    \
        double r2_ = r_ * r_;                                              \
        double Q0_ = fma(r_, 0.6931471805599453, 1.0);                     \
        double Q1_ = fma(r_, 0.05550410866482158, 0.24022650695910072);    \
        double Q2_ = fma(r_, 0.0013333558146428443, 0.009618129107628477); \
        double Q3_ = fma(r_, 1.525273380405984e-5, 1.5403530393381606e-4); \
        double r4_ = r2_ * r2_;                                            \
        double R0_ = fma(r2_, Q1_, Q0_);                                   \
        double S1_ = fma(r2_, Q3_, Q2_);                                   \
        double S2_ = fma(r4_, 1.3215486790144307e-6, S1_);                 \
        double P_  = fma(r4_, S2_, R0_);                                   \
        int ph_ = __double2hiint(P_) + (ni_ << 20);                        \
        res = __hiloint2double(ph_, __double2loint(P_));                   \
    }

// ---------------- setup: W_ih^T (f64), Etab = codebook@M, bias tables -----
__global__ __launch_bounds__(256) void setup_kernel(
        const float* __restrict__ W_ih, const float* __restrict__ codebook,
        const float* __restrict__ qs_W, const float* __restrict__ qs_b,
        const float* __restrict__ b_ih, const float* __restrict__ b_hh,
        double* __restrict__ W64T, double* __restrict__ Etab,
        double* __restrict__ ADD0, double* __restrict__ ADD1) {
    int tid = threadIdx.x;
    if (blockIdx.x == 0) {
        if (tid < NG) {
            int k = tid;
            double M0 = 0, M1 = 0, M2 = 0, qb = 0;
            for (int a = 0; a < ADIM; ++a) {
                double w = (double)W_ih[k * ADIM + a];
                M0 = fma(w, (double)qs_W[a * HD + 0], M0);
                M1 = fma(w, (double)qs_W[a * HD + 1], M1);
                M2 = fma(w, (double)qs_W[a * HD + 2], M2);
                qb = fma(w, (double)qs_b[a], qb);
            }
            for (int i = 0; i < NE; ++i) {   // Etab WITHOUT qb (qb in ADD1)
                double e = (double)codebook[i * HD + 0] * M0;
                e = fma((double)codebook[i * HD + 1], M1, e);
                e = fma((double)codebook[i * HD + 2], M2, e);
                Etab[i * NG + k] = e;
            }
            double bias = (double)b_ih[k] + (double)b_hh[k];
            ADD0[k] = bias;        // t == 0: no qs path
            ADD1[k] = bias + qb;   // t  > 0: qs_b @ W_ih^T folded in
        }
    } else {
        int i = (blockIdx.x - 1) * 256 + tid;   // 60*256 == ADIM*NG exactly
        int a = i / NG, kk = i % NG;
        W64T[i] = (double)W_ih[kk * ADIM + a];
    }
}

// ---------------- X = hs @ W_ih.T + bias(+qb)  (f64 accumulate) -----------
__global__ __launch_bounds__(256) void gemm_kernel(
        const float* __restrict__ hs, const double* __restrict__ W64T,
        const double* __restrict__ ADD0, const double* __restrict__ ADD1,
        double* __restrict__ X64) {
    int lane = threadIdx.x & 63;
    int wv = threadIdx.x >> 6;
    int cb = __builtin_amdgcn_readfirstlane(wv * 10);   // wave-uniform col base
    long row = (long)blockIdx.x * 64 + lane;            // < 131072
    const float* xr = hs + row * ADIM;
    double acc[10];
#pragma unroll
    for (int j = 0; j < 10; ++j) acc[j] = 0.0;
    for (int a0 = 0; a0 < ADIM; a0 += 4) {
        float4 xv = *(const float4*)(xr + a0);
#pragma unroll
        for (int u = 0; u < 4; ++u) {
            double xd = (double)((&xv.x)[u]);
            const double* wp = W64T + (a0 + u) * NG + cb;  // uniform -> broadcast
#pragma unroll
            for (int j = 0; j < 10; ++j) acc[j] = fma(wp[j], xd, acc[j]);
        }
    }
    int trow = (int)(row & (TT - 1));
    double* op = X64 + row * NG + cb;
#pragma unroll
    for (int j = 0; j < 10; ++j) {
        double a0j = ADD0[cb + j], a1j = ADD1[cb + j];
        op[j] = acc[j] + (trow == 0 ? a0j : a1j);
    }
}

// ---------------- sequential recurrence: one wave per batch ----------------
// QUAD layout: lane 4m+j holds gate j (i,f,g,o) of embedding m (m<10).
// All 4 lanes of quad m compute IDENTICAL c,h (quad-redundant) — the DPP
// argmax rotation reduce REQUIRES this redundancy (R3 bug: removing the
// i-gate broadcast corrupts the argmax keys on j!=0 lanes).
// Keep the whole serial cycle on the VALU: R5 showed SALU argmax/select
// (readlane->s_cmp/s_cselect->back) costs ~500 cyc/step in hazards.
__global__ __launch_bounds__(64) void recur_kernel(
        const double* __restrict__ X64,
        const float* __restrict__ W_hh, const double* __restrict__ Etab,
        float* __restrict__ h_out, int* __restrict__ idx_out) {
    const int k = threadIdx.x;
    const int b = blockIdx.x;
    const int j = k & 3;                 // gate type 0..3 = i,f,g,o
    const int m = k >> 2;                // embedding index (valid < 10)
    const bool valid = (k < NG);
    const int col = valid ? (j * 10 + m) : (NG - 1);
    const bool isg = (j == 2);

    const double LOG2E = 1.4426950408889634074;
    // i/f/o: e1 = e^{-gate}  -> act = 1/(1+e1)        (amul=1,  aadd=0)
    // g:     e1 = e^{+2gate} -> act = 1 - 2/(1+e1)    (amul=-2, aadd=1)
    const double Lg   = isg ? (2.0 * LOG2E) : (-LOG2E);
    const double amul = isg ? -2.0 : 1.0;
    const double aadd = isg ? 1.0 : 0.0;
    const double L2   = 2.0 * LOG2E;     // tanh(c): e^{+2|c|}

    double whh[NE];
#pragma unroll
    for (int mm = 0; mm < NE; ++mm) whh[mm] = (double)W_hh[col * NE + mm];
    double etab[NE];
#pragma unroll
    for (int i = 0; i < NE; ++i) etab[i] = Etab[i * NG + col];

    const double* Xb = X64 + (long)b * TT * NG;
    float* hob = h_out + (long)b * TT * NE;
    int* iob = idx_out + (long)b * TT;

    // prefetch ring depth 4 (t+4 overruns into W64T region: allocated, unused)
    double xs0 = Xb[0 * NG + col];
    double xs1 = Xb[1 * NG + col];
    double xs2 = Xb[2 * NG + col];
    double xs3 = Xb[3 * NG + col];

    double ha[NE];
#pragma unroll
    for (int mm = 0; mm < NE; ++mm) ha[mm] = 0.0;
    double c = 0.0, esel = 0.0;

    auto step = [&](double& xslot, int t) {
        double xg = xslot;
        xslot = Xb[(long)(t + 4) * NG + col];

        // gate = xg(+bias+qb folded in gemm) + esel + <h_prev, W_hh[col,:]>
        double p0 = fma(ha[1], whh[1], ha[0] * whh[0]);
        double p1 = fma(ha[3], whh[3], ha[2] * whh[2]);
        double p2 = fma(ha[5], whh[5], ha[4] * whh[4]);
        double p3 = fma(ha[7], whh[7], ha[6] * whh[6]);
        double p4 = fma(ha[9], whh[9], ha[8] * whh[8]);
        double dot = ((p0 + p1) + (p2 + p3)) + p4;
        double gate = (xg + esel) + dot;

        double e1;
        EXP2F64(e1, gate, Lg);
        double r1 = rcp1(1.0 + e1);
        double act = fma(amul, r1, aadd);

        // quad gather: broadcast ALL FOUR gates (quad-redundant c,h required)
        double fiv = dpp_mov_f64<0x00, 0xF>(act);
        double ffv = dpp_mov_f64<0x55, 0xF>(act);
        double fgv = dpp_mov_f64<0xAA, 0xF>(act);
        double fov = dpp_mov_f64<0xFF, 0xF>(act);
        c = fma(ffv, c, fiv * fgv);          // identical across quad

        double e2;
        EXP2F64(e2, fabs(c), L2);            // e^{+2|c|} in [1,inf)
        double r2 = rcp1(1.0 + e2);
        double th = fma(-2.0, r2, 1.0);      // tanh(|c|) in [0,1)
        double habs = fov * th;              // >= 0
        int hlo = __double2loint(habs);
        int hhi = __double2hiint(habs) | (__double2hiint(c) & 0x80000000);

        // argmax over m: pack (15-m) into low 4 mantissa bits, DPP max-reduce
        int klo = (hlo & ~15) | (15 - m);
        double key = __hiloint2double(hhi, klo);
        key = valid ? key : -1.0e300;
        key = fmax(key, dpp_mov_f64<0x124, 0xF>(key));  // row_ror:4
        key = fmax(key, dpp_mov_f64<0x128, 0xF>(key));  // row_ror:8
        key = fmax(key, dpp_mov_f64<0x142, 0xA>(key));  // bcast15 -> row1
        key = fmax(key, dpp_mov_f64<0x143, 0xC>(key));  // bcast31 -> rows2,3
        int slo = __builtin_amdgcn_readlane(__double2loint(key), 32);
        int s_idx = 15 - (slo & 15);         // wave-uniform argmax index

        // store h (lanes 4m, m<10) and idx (lane 40) in one masked store
        if ((k & 3) == 0 && k <= NG) {
            double hd = __hiloint2double(hhi, hlo);
            int val = valid ? __float_as_int((float)hd) : s_idx;
            int* ap = valid ? ((int*)hob + (long)t * NE + m) : (iob + t);
            *ap = val;
        }

        // broadcast h into SGPR-resident ha[] (quad-lane 4m per embedding)
#pragma unroll
        for (int mm = 0; mm < NE; ++mm) {
            int lo = __builtin_amdgcn_readlane(hlo, 4 * mm);
            int hi = __builtin_amdgcn_readlane(hhi, 4 * mm);
            ha[mm] = __hiloint2double(hi, lo);
        }
        // esel = etab[s_idx]: 4-level bit-tree select on VALU
        double a0 = (s_idx & 1) ? etab[1] : etab[0];
        double a1 = (s_idx & 1) ? etab[3] : etab[2];
        double a2 = (s_idx & 1) ? etab[5] : etab[4];
        double a3 = (s_idx & 1) ? etab[7] : etab[6];
        double a4 = (s_idx & 1) ? etab[9] : etab[8];
        double b0 = (s_idx & 2) ? a1 : a0;
        double b1 = (s_idx & 2) ? a3 : a2;
        double c0 = (s_idx & 4) ? b1 : b0;
        esel = (s_idx & 8) ? a4 : c0;
    };

    for (int t = 0; t < TT; t += 4) {
        step(xs0, t);
        step(xs1, t + 1);
        step(xs2, t + 2);
        step(xs3, t + 3);
    }
}

// ---------------- deferred: embs gather + NLL partial sums ----------------
__global__ __launch_bounds__(256) void tail_kernel(
        const float* __restrict__ h_ws, const int* __restrict__ idx_ws,
        const int* __restrict__ inds, const float* __restrict__ codebook,
        float* __restrict__ out_embs, double* __restrict__ partials) {
    int i = blockIdx.x * 256 + threadIdx.x;   // 512*256 == 131072 exactly
    int idx = idx_ws[i];
    out_embs[i * 3 + 0] = codebook[idx * 3 + 0];
    out_embs[i * 3 + 1] = codebook[idx * 3 + 1];
    out_embs[i * 3 + 2] = codebook[idx * 3 + 2];

    const float* hp = h_ws + (long)i * NE;
    double hv[NE];
#pragma unroll
    for (int mm = 0; mm < NE; ++mm) hv[mm] = (double)hp[mm];
    double mx = hv[0];
#pragma unroll
    for (int mm = 1; mm < NE; ++mm) mx = fmax(mx, hv[mm]);
    double sdn = 0.0;
#pragma unroll
    for (int mm = 0; mm < NE; ++mm) sdn += exp(hv[mm] - mx);
    int ind = inds[i];
    double picked = (double)hp[ind] - (mx + log(sdn));

    __shared__ double red[256];
    red[threadIdx.x] = picked;
    __syncthreads();
    for (int st = 128; st > 0; st >>= 1) {
        if (threadIdx.x < st) red[threadIdx.x] += red[threadIdx.x + st];
        __syncthreads();
    }
    if (threadIdx.x == 0) partials[blockIdx.x] = red[0];
}

__global__ __launch_bounds__(256) void final_kernel(
        const double* __restrict__ partials, float* __restrict__ out_loss) {
    __shared__ double red[256];
    red[threadIdx.x] = partials[threadIdx.x] + partials[threadIdx.x + 256];
    __syncthreads();
    for (int st = 128; st > 0; st >>= 1) {
        if (threadIdx.x < st) red[threadIdx.x] += red[threadIdx.x + st];
        __syncthreads();
    }
    if (threadIdx.x == 0)
        out_loss[0] = (float)(-red[0] / (double)(BB * TT));
}

extern "C" void kernel_launch(void* const* d_in, const int* in_sizes, int n_in,
                              void* d_out, int out_size, void* d_ws, size_t ws_size,
                              hipStream_t stream) {
    const float* hs       = (const float*)d_in[0];
    const int*   inds     = (const int*)d_in[1];
    const float* codebook = (const float*)d_in[2];
    const float* W_ih     = (const float*)d_in[3];
    const float* W_hh     = (const float*)d_in[4];
    const float* b_ih     = (const float*)d_in[5];
    const float* b_hh     = (const float*)d_in[6];
    const float* qs_W     = (const float*)d_in[7];
    const float* qs_b     = (const float*)d_in[8];
    float* out = (float*)d_out;

    char* ws = (char*)d_ws;
    double* X64   = (double*)(ws + OFF_X64);
    double* W64T  = (double*)(ws + OFF_W64T);
    double* Etab  = (double*)(ws + OFF_ETAB);
    double* ADD0  = (double*)(ws + OFF_ADD0);
    double* ADD1  = (double*)(ws + OFF_ADD1);
    float*  h_ws  = (float*)(ws + OFF_H);
    int*    idx_ws= (int*)(ws + OFF_IDX);
    double* part  = (double*)(ws + OFF_PART);

    setup_kernel<<<61, 256, 0, stream>>>(W_ih, codebook, qs_W, qs_b, b_ih, b_hh,
                                         W64T, Etab, ADD0, ADD1);
    gemm_kernel<<<2048, 256, 0, stream>>>(hs, W64T, ADD0, ADD1, X64);
    recur_kernel<<<BB, 64, 0, stream>>>(X64, W_hh, Etab, h_ws, idx_ws);
    tail_kernel<<<512, 256, 0, stream>>>(h_ws, idx_ws, inds, codebook, out, part);
    final_kernel<<<1, 256, 0, stream>>>(part, out + (size_t)BB * TT * HD);
}